// Round 1
// baseline (4924.496 us; speedup 1.0000x reference)
//
#include <hip/hip_runtime.h>

#define H    1024
#define OUTD 768
#define BSZ  512
#define TSTEPS 256
#define N3H  3072
#define NEXT 4864   // 4*H (interleaved gates) + OUTD (fc output columns)

typedef __attribute__((ext_vector_type(8))) short bf16x8;
typedef __attribute__((ext_vector_type(4))) float f32x4;

__device__ __forceinline__ unsigned short f2bf(float f){
  unsigned u = __builtin_bit_cast(unsigned, f);
  u += 0x7fffu + ((u >> 16) & 1u);           // round-to-nearest-even
  return (unsigned short)(u >> 16);
}
__device__ __forceinline__ float sigm(float x){ return 1.f/(1.f+__expf(-x)); }

// ---------------- conversion / assembly kernels ----------------
__global__ void conv_bf(unsigned short* dst, const float* src, int n){
  int i = blockIdx.x*256 + threadIdx.x;
  if (i < n) dst[i] = f2bf(src[i]);
}
// dst[r][c] = src[r*sstride + soff + c]  (bf16), r<rows, c<cols
__global__ void conv_rows(unsigned short* dst, const float* src, int rows, int cols,
                          int sstride, int soff){
  int i = blockIdx.x*256 + threadIdx.x;
  if (i < rows*cols){ int r = i/cols, c = i - r*cols; dst[i] = f2bf(src[r*sstride + soff + c]); }
}
// fcWT[k][o] = fc_W[o*2048 + k], k<1024 (h-dim), o<768 (out-dim)
__global__ void transp_fcw(unsigned short* dst, const float* fcw){
  __shared__ float tile[64][65];
  int k0 = blockIdx.x*64, o0 = blockIdx.y*64;
  int t = threadIdx.x; int rr = t>>2, cs = (t&3)*16;
  for (int j=0;j<16;j++) tile[rr][cs+j] = fcw[(size_t)(o0+rr)*2048 + k0+cs+j];
  __syncthreads();
  for (int j=0;j<16;j++) dst[(size_t)(k0+rr)*768 + o0+cs+j] = f2bf(tile[cs+j][rr]);
}

// W_ext (B^T layout, [NEXT][H] bf16). n<4096: gate-interleaved; n>=4096: fc_W h-half rows.
__global__ void asm_wext(unsigned short* Wext, const float* Wcomb, const float* Whh,
                         const float* fcW){
  int idx = blockIdx.x*256 + threadIdx.x;
  if (idx >= NEXT*H) return;
  int n = idx >> 10, k = idx & 1023;
  float v;
  if (n < 4096){
    int c = (n>>4)&3, jj = ((n>>6)<<4) | (n&15);
    if (c==0)      v = Wcomb[(size_t)jj*H + k]       + Whh[(size_t)jj*H + k];
    else if (c==1) v = Wcomb[(size_t)(H+jj)*H + k]   + Whh[(size_t)(H+jj)*H + k];
    else if (c==2) v = Wcomb[(size_t)(2*H+jj)*H + k];
    else           v = Whh[(size_t)(2*H+jj)*H + k];
  } else {
    v = fcW[(size_t)(n-4096)*2048 + k];
  }
  Wext[idx] = f2bf(v);
}

// const_ext [BSZ][NEXT] fp32
__global__ void asm_const(float* cst, const float* dmat, const float* fcctx,
                          const float* b_hh){
  int idx = blockIdx.x*256 + threadIdx.x;
  if (idx >= BSZ*NEXT) return;
  int b = idx / NEXT, n = idx - b*NEXT;
  float v;
  if (n < 4096){
    int c = (n>>4)&3, jj = ((n>>6)<<4) | (n&15);
    if (c==0)      v = dmat[(size_t)b*N3H + jj]       + b_hh[jj];
    else if (c==1) v = dmat[(size_t)b*N3H + H + jj]   + b_hh[H+jj];
    else if (c==2) v = dmat[(size_t)b*N3H + 2*H + jj];
    else           v = b_hh[2*H + jj];
  } else {
    v = fcctx[(size_t)b*OUTD + (n-4096)];
  }
  cst[idx] = v;
}

// step-0 GRU cell (direct form): gi/gh are [B][3H] fp32 with biases already added
__global__ void gru0(const float* gi, const float* gh, const float* hidden,
                     unsigned short* hbf, float* hf){
  int idx = blockIdx.x*256 + threadIdx.x;
  if (idx >= BSZ*H) return;
  int b = idx >> 10, j = idx & 1023;
  float r  = sigm(gi[(size_t)b*N3H + j]       + gh[(size_t)b*N3H + j]);
  float z  = sigm(gi[(size_t)b*N3H + H + j]   + gh[(size_t)b*N3H + H + j]);
  float nn = tanhf(gi[(size_t)b*N3H + 2*H + j] + r*gh[(size_t)b*N3H + 2*H + j]);
  float ho = hidden[idx];
  float hn = nn + z*(ho - nn);
  hf[idx] = hn; hbf[idx] = f2bf(hn);
}

// ---------------- generic bf16 MFMA GEMM: C[M,N] = A[M,K] x Bt[N,K]^T (+bias) ----------------
// 64x64 tile, BK=64, 256 threads = 4 waves; wave w owns rows 16w..16w+15 x all 64 cols.
__global__ __launch_bounds__(256) void gemm_bt(const unsigned short* __restrict__ A,
    const unsigned short* __restrict__ Bt, const float* __restrict__ bias,
    float* __restrict__ C, int N, int K){
  __shared__ unsigned short As[64][72];
  __shared__ unsigned short Bs[64][72];
  int tid = threadIdx.x, wave = tid>>6, lane = tid&63;
  int m0 = blockIdx.y*64, n0 = blockIdx.x*64;
  int lr = tid>>2, lc = (tid&3)*16;
  const unsigned short* Ag = A + (size_t)(m0+lr)*K + lc;
  const unsigned short* Bg = Bt + (size_t)(n0+lr)*K + lc;
  f32x4 acc[4];
  #pragma unroll
  for (int c=0;c<4;c++) acc[c] = (f32x4)0.f;
  int arow = wave*16 + (lane&15);
  int koff = (lane>>4)*8;
  for (int k0=0;k0<K;k0+=64){
    *(uint4*)&As[lr][lc]   = *(const uint4*)(Ag + k0);
    *(uint4*)&As[lr][lc+8] = *(const uint4*)(Ag + k0 + 8);
    *(uint4*)&Bs[lr][lc]   = *(const uint4*)(Bg + k0);
    *(uint4*)&Bs[lr][lc+8] = *(const uint4*)(Bg + k0 + 8);
    __syncthreads();
    #pragma unroll
    for (int kk=0;kk<2;kk++){
      bf16x8 af = *(const bf16x8*)&As[arow][kk*32 + koff];
      #pragma unroll
      for (int c=0;c<4;c++){
        bf16x8 bfr = *(const bf16x8*)&Bs[c*16 + (lane&15)][kk*32 + koff];
        acc[c] = __builtin_amdgcn_mfma_f32_16x16x32_bf16(af, bfr, acc[c], 0, 0, 0);
      }
    }
    __syncthreads();
  }
  int col = lane&15, rbase = m0 + wave*16 + (lane>>4)*4;
  #pragma unroll
  for (int c=0;c<4;c++){
    int n = n0 + c*16 + col;
    float bv = bias ? bias[n] : 0.f;
    #pragma unroll
    for (int i=0;i<4;i++) C[(size_t)(rbase+i)*N + n] = acc[c][i] + bv;
  }
}

// ---------------- fused recurrence step ----------------
// G = h_t @ W_ext + const;  gate tiles -> h_{t+1};  out tiles -> out[t-1]
__global__ __launch_bounds__(256) void gemm_step(const unsigned short* __restrict__ hbf,
    const float* __restrict__ hf, const unsigned short* __restrict__ Wext,
    const float* __restrict__ cst, float* __restrict__ outp,
    unsigned short* __restrict__ hbf_n, float* __restrict__ hf_n){
  __shared__ unsigned short As[64][72];
  __shared__ unsigned short Bs[64][72];
  int tid = threadIdx.x, wave = tid>>6, lane = tid&63;
  int m0 = blockIdx.y*64, n0 = blockIdx.x*64;
  int lr = tid>>2, lc = (tid&3)*16;
  const unsigned short* Ag = hbf + (size_t)(m0+lr)*H + lc;
  const unsigned short* Bg = Wext + (size_t)(n0+lr)*H + lc;
  f32x4 acc[4];
  #pragma unroll
  for (int c=0;c<4;c++) acc[c] = (f32x4)0.f;
  int arow = wave*16 + (lane&15);
  int koff = (lane>>4)*8;
  for (int k0=0;k0<H;k0+=64){
    *(uint4*)&As[lr][lc]   = *(const uint4*)(Ag + k0);
    *(uint4*)&As[lr][lc+8] = *(const uint4*)(Ag + k0 + 8);
    *(uint4*)&Bs[lr][lc]   = *(const uint4*)(Bg + k0);
    *(uint4*)&Bs[lr][lc+8] = *(const uint4*)(Bg + k0 + 8);
    __syncthreads();
    #pragma unroll
    for (int kk=0;kk<2;kk++){
      bf16x8 af = *(const bf16x8*)&As[arow][kk*32 + koff];
      #pragma unroll
      for (int c=0;c<4;c++){
        bf16x8 bfr = *(const bf16x8*)&Bs[c*16 + (lane&15)][kk*32 + koff];
        acc[c] = __builtin_amdgcn_mfma_f32_16x16x32_bf16(af, bfr, acc[c], 0, 0, 0);
      }
    }
    __syncthreads();
  }
  int nt = blockIdx.x;
  int col = lane&15;
  int rbase = m0 + wave*16 + (lane>>4)*4;
  if (nt < 64){
    // gate tile: 16-col sub-blocks are r, z, i_n, h_n for h-dims jj = nt*16 + col
    int jj = nt*16 + col;
    const float* cb = cst + nt*64 + col;
    #pragma unroll
    for (int i=0;i<4;i++){
      int b = rbase + i;
      const float* cr = cb + (size_t)b*NEXT;
      float r  = sigm(acc[0][i] + cr[0]);
      float z  = sigm(acc[1][i] + cr[16]);
      float nn = tanhf((acc[2][i] + cr[32]) + r*(acc[3][i] + cr[48]));
      float hn = nn + z*(hf[(size_t)b*H + jj] - nn);   // (1-z)*n + z*h
      hf_n[(size_t)b*H + jj]  = hn;
      hbf_n[(size_t)b*H + jj] = f2bf(hn);
    }
  } else {
    // output tile: fc(h_t) = out[t-1]
    int o0 = (nt-64)*64;
    #pragma unroll
    for (int c=0;c<4;c++){
      int oc = o0 + c*16 + col;
      #pragma unroll
      for (int i=0;i<4;i++){
        int b = rbase + i;
        outp[(size_t)b*OUTD + oc] = acc[c][i] + cst[(size_t)b*NEXT + 4096 + oc];
      }
    }
  }
}

// ---------------- host ----------------
extern "C" void kernel_launch(void* const* d_in, const int* in_sizes, int n_in,
                              void* d_out, int out_size, void* d_ws, size_t ws_size,
                              hipStream_t stream){
  const float* src    = (const float*)d_in[0];   // [1,512,768]
  const float* hidden = (const float*)d_in[1];   // [1,512,1024]
  const float* W_ih   = (const float*)d_in[2];   // [3072,768]
  const float* W_hh   = (const float*)d_in[3];   // [3072,1024]
  const float* b_ih   = (const float*)d_in[4];   // [3072]
  const float* b_hh   = (const float*)d_in[5];   // [3072]
  const float* fc_W   = (const float*)d_in[6];   // [768,2048]
  const float* fc_b   = (const float*)d_in[7];   // [768]
  float* outp = (float*)d_out;                   // [256,512,768]

  char* p = (char*)d_ws;
  auto alloc = [&](size_t bytes){ char* r = p; p += (bytes + 255) & ~(size_t)255; return r; };
  unsigned short* Wih_bf   = (unsigned short*)alloc((size_t)N3H*OUTD*2);
  unsigned short* Whh_bf   = (unsigned short*)alloc((size_t)N3H*H*2);
  unsigned short* fcWbt    = (unsigned short*)alloc((size_t)OUTD*H*2);   // fc_W ctx-half [768][1024]
  unsigned short* fcWT     = (unsigned short*)alloc((size_t)H*OUTD*2);   // fc_W h-half transposed [1024][768]
  unsigned short* ctx_bf   = (unsigned short*)alloc((size_t)BSZ*H*2);
  unsigned short* x0_bf    = (unsigned short*)alloc((size_t)BSZ*OUTD*2);
  float*          fcctx    = (float*)alloc((size_t)BSZ*OUTD*4);
  unsigned short* fcctx_bf = (unsigned short*)alloc((size_t)BSZ*OUTD*2);
  float*          Wcomb    = (float*)alloc((size_t)N3H*H*4);
  float*          dmat     = (float*)alloc((size_t)BSZ*N3H*4);
  unsigned short* Wext     = (unsigned short*)alloc((size_t)NEXT*H*2);
  float*          cst      = (float*)alloc((size_t)BSZ*NEXT*4);
  float*          gi       = (float*)alloc((size_t)BSZ*N3H*4);
  float*          gh       = (float*)alloc((size_t)BSZ*N3H*4);
  unsigned short* hbf      = (unsigned short*)alloc((size_t)2*BSZ*H*2);
  float*          hf       = (float*)alloc((size_t)2*BSZ*H*4);

  auto cdiv = [](int a, int b){ return (a + b - 1)/b; };

  // --- prologue: conversions ---
  conv_bf<<<cdiv(N3H*OUTD,256),256,0,stream>>>(Wih_bf, W_ih, N3H*OUTD);
  conv_bf<<<cdiv(N3H*H,256),256,0,stream>>>(Whh_bf, W_hh, N3H*H);
  conv_bf<<<cdiv(BSZ*H,256),256,0,stream>>>(ctx_bf, hidden, BSZ*H);
  conv_bf<<<cdiv(BSZ*OUTD,256),256,0,stream>>>(x0_bf, src, BSZ*OUTD);
  conv_rows<<<cdiv(OUTD*H,256),256,0,stream>>>(fcWbt, fc_W, OUTD, H, 2*H, H);
  transp_fcw<<<dim3(16,12),256,0,stream>>>(fcWT, fc_W);

  // --- prologue: weight-folding GEMMs ---
  // Wcomb[3072,1024] = W_ih[3072,768] @ fcW_h[768,1024]  (Bt = fcWT)
  gemm_bt<<<dim3(H/64, N3H/64),256,0,stream>>>(Wih_bf, fcWT, nullptr, Wcomb, H, OUTD);
  // fcctx[512,768] = ctx[512,1024] @ fcW_ctx.T + fc_b    (Bt = fcWbt)
  gemm_bt<<<dim3(OUTD/64, BSZ/64),256,0,stream>>>(ctx_bf, fcWbt, fc_b, fcctx, OUTD, H);
  conv_bf<<<cdiv(BSZ*OUTD,256),256,0,stream>>>(fcctx_bf, fcctx, BSZ*OUTD);
  // dmat[512,3072] = fcctx[512,768] @ W_ih.T + b_ih      (Bt = Wih_bf)
  gemm_bt<<<dim3(N3H/64, BSZ/64),256,0,stream>>>(fcctx_bf, Wih_bf, b_ih, dmat, N3H, OUTD);

  asm_wext<<<cdiv(NEXT*H,256),256,0,stream>>>(Wext, Wcomb, W_hh, fc_W);
  asm_const<<<cdiv(BSZ*NEXT,256),256,0,stream>>>(cst, dmat, fcctx, b_hh);

  // --- step 0 (direct form, x0 = src[0]) ---
  gemm_bt<<<dim3(N3H/64, BSZ/64),256,0,stream>>>(x0_bf, Wih_bf, b_ih, gi, N3H, OUTD);
  gemm_bt<<<dim3(N3H/64, BSZ/64),256,0,stream>>>(ctx_bf, Whh_bf, b_hh, gh, N3H, H);
  gru0<<<cdiv(BSZ*H,256),256,0,stream>>>(gi, gh, hidden, hbf + (size_t)BSZ*H, hf + (size_t)BSZ*H);

  // --- recurrence: K_t reads h_t -> writes out[t-1] and h_{t+1} ---
  for (int t=1; t<=TSTEPS; t++){
    const unsigned short* hin  = hbf + (size_t)(t&1)*BSZ*H;
    const float*          hfin = hf  + (size_t)(t&1)*BSZ*H;
    unsigned short* hout  = hbf + (size_t)((t+1)&1)*BSZ*H;
    float*          hfout = hf  + (size_t)((t+1)&1)*BSZ*H;
    gemm_step<<<dim3(NEXT/64, BSZ/64),256,0,stream>>>(hin, hfin, Wext, cst,
        outp + (size_t)(t-1)*BSZ*OUTD, hout, hfout);
  }
}